// Round 2
// baseline (18.499 us; speedup 1.0000x reference)
//
#include <hip/hip_runtime.h>

// Reference: x (64, 4096, 128) f32. window = x[54:64] along axis 0.
// 32 steps: new = mean(window, axis=0); window = shift+append(new).
// Output: (32, 4096, 128) f32. Per-position independent recurrence.
//
// Memory-bound: 20 MB read + 64 MB write. Strategy: float2/thread
// (16 waves/CU for latency hiding), running-sum recurrence fully in
// registers (unrolled so w[t%10] is a static index), non-temporal
// loads/stores (data is touch-once, keep it out of L2).

#define SEQ        64
#define NPOS       (4096 * 128)   // 524288 positions per time-slice
#define RA_WINDOW  10
#define HORIZON    32

typedef float f32x2 __attribute__((ext_vector_type(2)));

__global__ __launch_bounds__(256) void rolling_avg_kernel(
    const f32x2* __restrict__ x, f32x2* __restrict__ out)
{
    const int p = blockIdx.x * blockDim.x + threadIdx.x;   // float2 index
    const int n2 = NPOS / 2;                               // 262144
    if (p >= n2) return;

    const f32x2* __restrict__ xin = x + (size_t)(SEQ - RA_WINDOW) * n2 + p;
    f32x2* __restrict__ o = out + p;

    // Load the 10-deep window (coalesced, 8 B/lane, non-temporal).
    f32x2 w[RA_WINDOW];
    #pragma unroll
    for (int k = 0; k < RA_WINDOW; ++k)
        w[k] = __builtin_nontemporal_load(&xin[(size_t)k * n2]);

    // Running sum of the window.
    f32x2 s = (f32x2)(0.0f, 0.0f);
    #pragma unroll
    for (int k = 0; k < RA_WINDOW; ++k)
        s += w[k];

    const float inv = 1.0f / (float)RA_WINDOW;

    // Fully unrolled so w[t % 10] is a compile-time register index.
    #pragma unroll
    for (int t = 0; t < HORIZON; ++t) {
        f32x2 nw = s * inv;
        __builtin_nontemporal_store(nw, &o[(size_t)t * n2]);
        const int idx = t % RA_WINDOW;
        s += nw - w[idx];
        w[idx] = nw;
    }
}

extern "C" void kernel_launch(void* const* d_in, const int* in_sizes, int n_in,
                              void* d_out, int out_size, void* d_ws, size_t ws_size,
                              hipStream_t stream) {
    const f32x2* x = (const f32x2*)d_in[0];
    f32x2* out = (f32x2*)d_out;

    const int threads = 256;
    const int blocks = (NPOS / 2 + threads - 1) / threads;   // 1024
    rolling_avg_kernel<<<blocks, threads, 0, stream>>>(x, out);
}

// Round 3
// 18.488 us; speedup vs baseline: 1.0006x; 1.0006x over previous
//
#include <hip/hip_runtime.h>

// Reference: x (64, 4096, 128) f32. window = x[54:64] along axis 0.
// 32 steps: new = mean(window); window = shift+append(new).
// Output: (32, 4096, 128) f32.
//
// R3 probe: compute ALL 32 outputs into registers first (recurrence fully
// unrolled, static indices), then burst 32 back-to-back dwordx4 stores with
// no intervening VALU — isolates "store stream purity" vs R1's interleaved
// store+chain. Traffic is irreducible (20 MB R + 64 MB W).

#define SEQ        64
#define NPOS       (4096 * 128)
#define RA_WINDOW  10
#define HORIZON    32

__global__ __launch_bounds__(256) void rolling_avg_kernel(
    const float4* __restrict__ x, float4* __restrict__ out)
{
    const int p = blockIdx.x * blockDim.x + threadIdx.x;   // float4 index
    const int n4 = NPOS / 4;                               // 131072
    if (p >= n4) return;

    const float4* __restrict__ xin = x + (size_t)(SEQ - RA_WINDOW) * n4 + p;
    float4* __restrict__ o = out + p;

    // Load 10-deep window (coalesced, 16 B/lane).
    float4 w[RA_WINDOW];
    #pragma unroll
    for (int k = 0; k < RA_WINDOW; ++k)
        w[k] = xin[(size_t)k * n4];

    float4 s;
    s.x = s.y = s.z = s.w = 0.0f;
    #pragma unroll
    for (int k = 0; k < RA_WINDOW; ++k) {
        s.x += w[k].x; s.y += w[k].y; s.z += w[k].z; s.w += w[k].w;
    }

    const float inv = 1.0f / (float)RA_WINDOW;

    // Phase 1: compute all 32 outputs into registers (no stores yet).
    float4 r[HORIZON];
    #pragma unroll
    for (int t = 0; t < HORIZON; ++t) {
        float4 nw;
        nw.x = s.x * inv; nw.y = s.y * inv; nw.z = s.z * inv; nw.w = s.w * inv;
        r[t] = nw;
        const int idx = t % RA_WINDOW;
        s.x += nw.x - w[idx].x;
        s.y += nw.y - w[idx].y;
        s.z += nw.z - w[idx].z;
        s.w += nw.w - w[idx].w;
        w[idx] = nw;
    }

    // Phase 2: pure store burst, 32 x dwordx4 back-to-back.
    #pragma unroll
    for (int t = 0; t < HORIZON; ++t)
        o[(size_t)t * n4] = r[t];
}

extern "C" void kernel_launch(void* const* d_in, const int* in_sizes, int n_in,
                              void* d_out, int out_size, void* d_ws, size_t ws_size,
                              hipStream_t stream) {
    const float4* x = (const float4*)d_in[0];
    float4* out = (float4*)d_out;

    const int threads = 256;
    const int blocks = (NPOS / 4 + threads - 1) / threads;   // 512
    rolling_avg_kernel<<<blocks, threads, 0, stream>>>(x, out);
}